// Round 11
// baseline (105.159 us; speedup 1.0000x reference)
//
#include <hip/hip_runtime.h>
#include <hip/hip_fp16.h>
#include <math.h>

// Problem constants: B=4, M=4096, D=64, W=128
constexpr int B = 4;
constexpr int M = 4096;
constexpr int D = 64;
constexpr int W = 128;
constexpr int NELEM = B * M * D;   // 1,048,576 per tensor

// Split-half-plane layout: each 128B fp16 row is stored as two 64B halves
// in separate planes. Plane offsets differ by (1MB + 256B) so the two
// halves of a row map to ADJACENT (different) 256B-interleaved L2 channels
// instead of the same one. v planes shifted by another 512B.
constexpr size_t HP  = (size_t)B * M * 64;      // 1 MiB half-plane
constexpr size_t K0O = 0;
constexpr size_t K1O = HP + 256;
constexpr size_t V0O = 2 * HP + 512;
constexpr size_t V1O = 3 * HP + 768;
constexpr size_t WS_NEED = 4 * HP + 768;

typedef _Float16 h2_t __attribute__((ext_vector_type(2)));
typedef int      i4_t __attribute__((ext_vector_type(4)));

// ---- pass 1: fp32 k,v -> fp16 split-half planes ----
// thread: tensor (k/v), row g, half, chunk(16B). 262144 threads total.
__global__ __launch_bounds__(256) void cvt_split(
    const float4* __restrict__ k, const float4* __restrict__ v,
    char* __restrict__ ws) {
    int id = blockIdx.x * 256 + threadIdx.x;
    if (id >= 2 * B * M * 8) return;
    const int tensor = id >> 17;           // 131072 threads per tensor
    const int j      = id & 131071;
    const int g      = j >> 3;             // global row
    const int half   = (j >> 2) & 1;
    const int chunk  = j & 3;
    const float4* src = tensor ? v : k;
    float4 f0 = src[g * 16 + half * 8 + chunk * 2];
    float4 f1 = src[g * 16 + half * 8 + chunk * 2 + 1];
    union { __half2 h[4]; i4_t v4; } u;
    u.h[0] = __floats2half2_rn(f0.x, f0.y);
    u.h[1] = __floats2half2_rn(f0.z, f0.w);
    u.h[2] = __floats2half2_rn(f1.x, f1.y);
    u.h[3] = __floats2half2_rn(f1.z, f1.w);
    const size_t base = (tensor ? V0O : K0O) + (half ? (HP + 256) : 0);
    *(i4_t*)(ws + base + (size_t)g * 64 + chunk * 16) = u.v4;
}

// ---- main kernel: R6 structure verbatim, split-plane addressing ----
// One WAVE per (b,m) row; 4 waves per block; grid = B*M/4.
// Lane (ci,r): ci=lane&7 owns dims [ci*8,+8): half = ci>>2, chunk = ci&3;
// r=lane>>3 covers rows w ≡ r (mod 8). nt gathers, fdot2 k-dots,
// in-register softmax, v batch issued before the softmax chain.
__global__ __launch_bounds__(256, 4) void sparse_attn_f16(
    const float* __restrict__ q,
    const char*  __restrict__ ws,
    const int*   __restrict__ idx,
    float*       __restrict__ out)
{
    const int blk  = blockIdx.x;
    const int b    = blk & 3;              // XCD round-robin -> fixed b per XCD
    const int mb   = (blk >> 2) * 4;
    const int t    = threadIdx.x;
    const int wave = t >> 6;
    const int lane = t & 63;
    const int ci   = lane & 7;
    const int r    = lane >> 3;
    const int m    = mb + wave;
    const int chunk = ci & 3;

    __shared__ int idx_s[4 * W];

    ((int2*)idx_s)[t] = ((const int2*)(idx + (size_t)mb * W))[t];

    // q chunk (dims [ci*8, ci*8+8)) as 4x half2 for fdot2
    const float* qrow = q + ((size_t)b * M + m) * D;
    const float4 qa = ((const float4*)qrow)[2 * ci];
    const float4 qb = ((const float4*)qrow)[2 * ci + 1];
    h2_t qh[4];
    qh[0] = (h2_t){(_Float16)qa.x, (_Float16)qa.y};
    qh[1] = (h2_t){(_Float16)qa.z, (_Float16)qa.w};
    qh[2] = (h2_t){(_Float16)qb.x, (_Float16)qb.y};
    qh[3] = (h2_t){(_Float16)qb.z, (_Float16)qb.w};

    __syncthreads();   // the only barrier

    // per-lane plane bases (batch offset folded in, wave-uniform part)
    const size_t boff = (size_t)b * M * 64;
    const char* kb = ws + (ci >= 4 ? K1O : K0O) + boff;
    const char* vb = ws + (ci >= 4 ? V1O : V0O) + boff;

    // 32-bit byte offsets within a half-plane; shared by k and v.
    int voff[16];
    #pragma unroll
    for (int j = 0; j < 16; ++j)
        voff[j] = idx_s[wave * W + j * 8 + r] * 64 + chunk * 16;

    // ---- logits: 2 register batches of 8 nt gathers + fdot2 ----
    float larr[16];
    #pragma unroll
    for (int batch = 0; batch < 2; ++batch) {
        i4_t kreg[8];
        #pragma unroll
        for (int jj = 0; jj < 8; ++jj)
            kreg[jj] = __builtin_nontemporal_load(
                (const i4_t*)(kb + voff[batch * 8 + jj]));
        #pragma unroll
        for (int jj = 0; jj < 8; ++jj) {
            union { i4_t v; h2_t h[4]; } u;
            u.v = kreg[jj];
            float part = 0.f;
            part = __builtin_amdgcn_fdot2(u.h[0], qh[0], part, false);
            part = __builtin_amdgcn_fdot2(u.h[1], qh[1], part, false);
            part = __builtin_amdgcn_fdot2(u.h[2], qh[2], part, false);
            part = __builtin_amdgcn_fdot2(u.h[3], qh[3], part, false);
            part += __shfl_xor(part, 1);
            part += __shfl_xor(part, 2);
            part += __shfl_xor(part, 4);
            larr[batch * 8 + jj] = part;   // logit for w = (batch*8+jj)*8 + r
        }
    }

    // ---- issue first v batch; softmax chain hides its latency ----
    i4_t vreg0[8];
    #pragma unroll
    for (int jj = 0; jj < 8; ++jj)
        vreg0[jj] = __builtin_nontemporal_load((const i4_t*)(vb + voff[jj]));

    // ---- softmax, fully in-register ----
    float mx = larr[0];
    #pragma unroll
    for (int j = 1; j < 16; ++j) mx = fmaxf(mx, larr[j]);
    mx = fmaxf(mx, __shfl_xor(mx, 8));
    mx = fmaxf(mx, __shfl_xor(mx, 16));
    mx = fmaxf(mx, __shfl_xor(mx, 32));

    float sum = 0.f;
    #pragma unroll
    for (int j = 0; j < 16; ++j) { larr[j] = __expf(larr[j] - mx); sum += larr[j]; }
    sum += __shfl_xor(sum, 8);
    sum += __shfl_xor(sum, 16);
    sum += __shfl_xor(sum, 32);
    const float inv = 1.0f / sum;   // folded into the final store

    // ---- weighted V accumulate (batch 1 issued while batch 0 consumed) ----
    float acc[8] = {0, 0, 0, 0, 0, 0, 0, 0};
    i4_t vreg1[8];
    #pragma unroll
    for (int jj = 0; jj < 8; ++jj)
        vreg1[jj] = __builtin_nontemporal_load((const i4_t*)(vb + voff[8 + jj]));

    #pragma unroll
    for (int jj = 0; jj < 8; ++jj) {
        const float p = larr[jj];
        union { i4_t v; h2_t h[4]; } u;
        u.v = vreg0[jj];
        #pragma unroll
        for (int c = 0; c < 4; ++c) {
            float2 f = __half22float2(*(const __half2*)&u.h[c]);
            acc[2 * c]     += p * f.x;
            acc[2 * c + 1] += p * f.y;
        }
    }
    #pragma unroll
    for (int jj = 0; jj < 8; ++jj) {
        const float p = larr[8 + jj];
        union { i4_t v; h2_t h[4]; } u;
        u.v = vreg1[jj];
        #pragma unroll
        for (int c = 0; c < 4; ++c) {
            float2 f = __half22float2(*(const __half2*)&u.h[c]);
            acc[2 * c]     += p * f.x;
            acc[2 * c + 1] += p * f.y;
        }
    }
    #pragma unroll
    for (int o = 8; o < 64; o <<= 1) {
        #pragma unroll
        for (int i = 0; i < 8; ++i) acc[i] += __shfl_xor(acc[i], o);
    }

    if (r == 0) {
        float4* orow = (float4*)(out + ((size_t)b * M + m) * D);
        orow[2 * ci]     = make_float4(acc[0] * inv, acc[1] * inv,
                                       acc[2] * inv, acc[3] * inv);
        orow[2 * ci + 1] = make_float4(acc[4] * inv, acc[5] * inv,
                                       acc[6] * inv, acc[7] * inv);
    }
}

// ---- fallback fp32 kernel (R1 structure) if workspace too small ----
__global__ __launch_bounds__(128) void sparse_attn_f32(
    const float* __restrict__ q,
    const float* __restrict__ k,
    const float* __restrict__ v,
    const int*   __restrict__ idx,
    float*       __restrict__ out)
{
    const int blk = blockIdx.x;
    const int b = blk & 3;
    const int m = blk >> 2;
    const int t = threadIdx.x;
    const int lane = t & 63;
    const int wave = t >> 6;
    const int ci = lane & 15;
    const int r  = lane >> 4;

    __shared__ int   idx_s[W];
    __shared__ float sc_s[W];
    __shared__ float red_s[4];
    __shared__ float4 opart_s[16];

    idx_s[t] = idx[m * W + t];
    const float4 qf = ((const float4*)(q + ((size_t)b * M + m) * D))[ci];
    __syncthreads();

    const float* kb = k + (size_t)b * M * D;
    const int wbase = wave * 64;

    #pragma unroll
    for (int j = 0; j < 16; ++j) {
        const int w = wbase + j * 4 + r;
        const float4 kv = ((const float4*)(kb + (size_t)idx_s[w] * D))[ci];
        float part = kv.x * qf.x + kv.y * qf.y + kv.z * qf.z + kv.w * qf.w;
        part += __shfl_xor(part, 1);
        part += __shfl_xor(part, 2);
        part += __shfl_xor(part, 4);
        part += __shfl_xor(part, 8);
        if (ci == 0) sc_s[w] = part;
    }
    __syncthreads();

    float logit = sc_s[t];
    float mx = logit;
    #pragma unroll
    for (int o = 1; o < 64; o <<= 1) mx = fmaxf(mx, __shfl_xor(mx, o));
    if (lane == 0) red_s[wave] = mx;
    __syncthreads();
    mx = fmaxf(red_s[0], red_s[1]);
    float e = __expf(logit - mx);
    float sm = e;
    #pragma unroll
    for (int o = 1; o < 64; o <<= 1) sm += __shfl_xor(sm, o);
    if (lane == 0) red_s[2 + wave] = sm;
    __syncthreads();
    const float inv_denom = 1.0f / (red_s[2] + red_s[3]);
    sc_s[t] = e * inv_denom;
    __syncthreads();

    const float* vb = v + (size_t)b * M * D;
    float4 acc = {0.f, 0.f, 0.f, 0.f};
    #pragma unroll
    for (int j = 0; j < 16; ++j) {
        const int w = wbase + j * 4 + r;
        const float p = sc_s[w];
        const float4 vv = ((const float4*)(vb + (size_t)idx_s[w] * D))[ci];
        acc.x += p * vv.x; acc.y += p * vv.y;
        acc.z += p * vv.z; acc.w += p * vv.w;
    }
    acc.x += __shfl_xor(acc.x, 16); acc.y += __shfl_xor(acc.y, 16);
    acc.z += __shfl_xor(acc.z, 16); acc.w += __shfl_xor(acc.w, 16);
    acc.x += __shfl_xor(acc.x, 32); acc.y += __shfl_xor(acc.y, 32);
    acc.z += __shfl_xor(acc.z, 32); acc.w += __shfl_xor(acc.w, 32);

    if (wave == 0 && r == 0) opart_s[ci] = acc;
    __syncthreads();
    if (wave == 1 && r == 0) {
        const float4 o0 = opart_s[ci];
        float4 res;
        res.x = o0.x + acc.x; res.y = o0.y + acc.y;
        res.z = o0.z + acc.z; res.w = o0.w + acc.w;
        ((float4*)(out + ((size_t)b * M + m) * D))[ci] = res;
    }
}

extern "C" void kernel_launch(void* const* d_in, const int* in_sizes, int n_in,
                              void* d_out, int out_size, void* d_ws, size_t ws_size,
                              hipStream_t stream) {
    const float* q = (const float*)d_in[0];
    const float* k = (const float*)d_in[1];
    const float* v = (const float*)d_in[2];
    const int* idx = (const int*)d_in[3];
    float* out = (float*)d_out;

    if (ws_size >= WS_NEED) {
        char* ws = (char*)d_ws;
        const int nthreads = 2 * B * M * 8;    // 262144
        cvt_split<<<(nthreads + 255) / 256, 256, 0, stream>>>(
            (const float4*)k, (const float4*)v, ws);
        sparse_attn_f16<<<B * M / 4, 256, 0, stream>>>(q, ws, idx, out);
    } else {
        sparse_attn_f32<<<B * M, 128, 0, stream>>>(q, k, v, idx, out);
    }
}

// Round 12
// 95.766 us; speedup vs baseline: 1.0981x; 1.0981x over previous
//
#include <hip/hip_runtime.h>
#include <hip/hip_fp16.h>
#include <math.h>

// Problem constants: B=4, M=4096, D=64, W=128
constexpr int B = 4;
constexpr int M = 4096;
constexpr int D = 64;
constexpr int W = 128;
constexpr int NELEM = B * M * D;   // 1,048,576 per tensor

typedef _Float16 h2_t __attribute__((ext_vector_type(2)));
typedef int      i4_t __attribute__((ext_vector_type(4)));

// ---- pass 1: fp32 -> fp16 of k AND v in a single launch ----
__global__ __launch_bounds__(256) void cvt_f32_f16_2(
    const float4* __restrict__ k, const float4* __restrict__ v,
    __half2* __restrict__ kh, __half2* __restrict__ vh, int n4) {
    int i = blockIdx.x * 256 + threadIdx.x;
    const float4* src;
    __half2* dst;
    if (i < n4) { src = k; dst = kh; }
    else        { src = v; dst = vh; i -= n4; if (i >= n4) return; }
    float4 f = src[i];
    dst[2 * i]     = __floats2half2_rn(f.x, f.y);
    dst[2 * i + 1] = __floats2half2_rn(f.z, f.w);
}

// ---- main kernel: R6 structure, 128-THREAD blocks + fp16 pk accumulation --
// One WAVE per (b,m) row; 2 waves per block; grid = B*M/2 (8192 blocks ->
// finer scheduling quanta; R1/R2's 128-thr kernels held 72-78% occupancy
// vs 33% for all 256-thr variants). Lane (ci,r): ci=lane&7 owns 16B chunk,
// r=lane>>3 covers rows w ≡ r (mod 8). nt gathers, fdot2 k-dots,
// in-register softmax; v accumulated as packed fp16 (v_pk_fma_f16) and
// reduced packed (12 shuffles instead of 48) -> ~40% VALU cut.
__global__ __launch_bounds__(128, 4) void sparse_attn_f16(
    const float* __restrict__ q,
    const __half* __restrict__ kh,
    const __half* __restrict__ vh,
    const int*   __restrict__ idx,
    float*       __restrict__ out)
{
    const int blk  = blockIdx.x;
    const int b    = blk & 3;              // constant per XCD (blk%8 -> b=x&3)
    const int mb   = (blk >> 2) * 2;       // 2 m rows per block
    const int t    = threadIdx.x;          // 0..127
    const int wave = t >> 6;
    const int lane = t & 63;
    const int ci   = lane & 7;
    const int r    = lane >> 3;
    const int m    = mb + wave;

    __shared__ int idx_s[2 * W];           // 1 KB

    ((int2*)idx_s)[t] = ((const int2*)(idx + (size_t)mb * W))[t];

    // q chunk (dims [ci*8, ci*8+8)) as 4x half2 for fdot2
    const float* qrow = q + ((size_t)b * M + m) * D;
    const float4 qa = ((const float4*)qrow)[2 * ci];
    const float4 qb = ((const float4*)qrow)[2 * ci + 1];
    h2_t qh[4];
    qh[0] = (h2_t){(_Float16)qa.x, (_Float16)qa.y};
    qh[1] = (h2_t){(_Float16)qa.z, (_Float16)qa.w};
    qh[2] = (h2_t){(_Float16)qb.x, (_Float16)qb.y};
    qh[3] = (h2_t){(_Float16)qb.z, (_Float16)qb.w};

    __syncthreads();   // the only barrier

    // 32-bit byte offsets into the batch's fp16 planes; reused for k and v.
    int voff[16];
    #pragma unroll
    for (int j = 0; j < 16; ++j)
        voff[j] = idx_s[wave * W + j * 8 + r] * (D * 2) + ci * 16;

    const char* kb = (const char*)(kh + (size_t)b * M * D);
    const char* vb = (const char*)(vh + (size_t)b * M * D);

    // ---- logits: 2 register batches of 8 nt gathers + fdot2 ----
    float larr[16];
    #pragma unroll
    for (int batch = 0; batch < 2; ++batch) {
        i4_t kreg[8];
        #pragma unroll
        for (int jj = 0; jj < 8; ++jj)
            kreg[jj] = __builtin_nontemporal_load(
                (const i4_t*)(kb + voff[batch * 8 + jj]));
        #pragma unroll
        for (int jj = 0; jj < 8; ++jj) {
            union { i4_t v; h2_t h[4]; } u;
            u.v = kreg[jj];
            float part = 0.f;
            part = __builtin_amdgcn_fdot2(u.h[0], qh[0], part, false);
            part = __builtin_amdgcn_fdot2(u.h[1], qh[1], part, false);
            part = __builtin_amdgcn_fdot2(u.h[2], qh[2], part, false);
            part = __builtin_amdgcn_fdot2(u.h[3], qh[3], part, false);
            part += __shfl_xor(part, 1);
            part += __shfl_xor(part, 2);
            part += __shfl_xor(part, 4);
            larr[batch * 8 + jj] = part;   // logit for w = (batch*8+jj)*8 + r
        }
    }

    // ---- issue first v batch; softmax chain hides its latency ----
    i4_t vreg0[8];
    #pragma unroll
    for (int jj = 0; jj < 8; ++jj)
        vreg0[jj] = __builtin_nontemporal_load((const i4_t*)(vb + voff[jj]));

    // ---- softmax, fully in-register ----
    float mx = larr[0];
    #pragma unroll
    for (int j = 1; j < 16; ++j) mx = fmaxf(mx, larr[j]);
    mx = fmaxf(mx, __shfl_xor(mx, 8));
    mx = fmaxf(mx, __shfl_xor(mx, 16));
    mx = fmaxf(mx, __shfl_xor(mx, 32));

    float sum = 0.f;
    #pragma unroll
    for (int j = 0; j < 16; ++j) { larr[j] = __expf(larr[j] - mx); sum += larr[j]; }
    sum += __shfl_xor(sum, 8);
    sum += __shfl_xor(sum, 16);
    sum += __shfl_xor(sum, 32);
    const float inv = 1.0f / sum;   // applied at the final store

    // ---- weighted V accumulate, PACKED fp16 (v_pk_fma_f16) ----
    h2_t acc[4] = {(h2_t)0, (h2_t)0, (h2_t)0, (h2_t)0};
    i4_t vreg1[8];
    #pragma unroll
    for (int jj = 0; jj < 8; ++jj)
        vreg1[jj] = __builtin_nontemporal_load((const i4_t*)(vb + voff[8 + jj]));

    #pragma unroll
    for (int jj = 0; jj < 8; ++jj) {
        const _Float16 ph = (_Float16)larr[jj];
        const h2_t pv = (h2_t){ph, ph};
        union { i4_t v; h2_t h[4]; } u;
        u.v = vreg0[jj];
        #pragma unroll
        for (int c = 0; c < 4; ++c) acc[c] += pv * u.h[c];
    }
    #pragma unroll
    for (int jj = 0; jj < 8; ++jj) {
        const _Float16 ph = (_Float16)larr[8 + jj];
        const h2_t pv = (h2_t){ph, ph};
        union { i4_t v; h2_t h[4]; } u;
        u.v = vreg1[jj];
        #pragma unroll
        for (int c = 0; c < 4; ++c) acc[c] += pv * u.h[c];
    }
    // packed cross-lane reduce over the 8 row-groups (ci preserved)
    #pragma unroll
    for (int o = 8; o < 64; o <<= 1) {
        #pragma unroll
        for (int c = 0; c < 4; ++c) {
            union { h2_t h; int i; } s;
            s.h = acc[c];
            s.i = __shfl_xor(s.i, o);
            acc[c] += s.h;
        }
    }

    if (r == 0) {
        float4* orow = (float4*)(out + ((size_t)b * M + m) * D);
        orow[2 * ci]     = make_float4((float)acc[0][0] * inv,
                                       (float)acc[0][1] * inv,
                                       (float)acc[1][0] * inv,
                                       (float)acc[1][1] * inv);
        orow[2 * ci + 1] = make_float4((float)acc[2][0] * inv,
                                       (float)acc[2][1] * inv,
                                       (float)acc[3][0] * inv,
                                       (float)acc[3][1] * inv);
    }
}

// ---- fallback fp32 kernel (R1 structure) if workspace too small ----
__global__ __launch_bounds__(128) void sparse_attn_f32(
    const float* __restrict__ q,
    const float* __restrict__ k,
    const float* __restrict__ v,
    const int*   __restrict__ idx,
    float*       __restrict__ out)
{
    const int blk = blockIdx.x;
    const int b = blk & 3;
    const int m = blk >> 2;
    const int t = threadIdx.x;
    const int lane = t & 63;
    const int wave = t >> 6;
    const int ci = lane & 15;
    const int r  = lane >> 4;

    __shared__ int   idx_s[W];
    __shared__ float sc_s[W];
    __shared__ float red_s[4];
    __shared__ float4 opart_s[16];

    idx_s[t] = idx[m * W + t];
    const float4 qf = ((const float4*)(q + ((size_t)b * M + m) * D))[ci];
    __syncthreads();

    const float* kb = k + (size_t)b * M * D;
    const int wbase = wave * 64;

    #pragma unroll
    for (int j = 0; j < 16; ++j) {
        const int w = wbase + j * 4 + r;
        const float4 kv = ((const float4*)(kb + (size_t)idx_s[w] * D))[ci];
        float part = kv.x * qf.x + kv.y * qf.y + kv.z * qf.z + kv.w * qf.w;
        part += __shfl_xor(part, 1);
        part += __shfl_xor(part, 2);
        part += __shfl_xor(part, 4);
        part += __shfl_xor(part, 8);
        if (ci == 0) sc_s[w] = part;
    }
    __syncthreads();

    float logit = sc_s[t];
    float mx = logit;
    #pragma unroll
    for (int o = 1; o < 64; o <<= 1) mx = fmaxf(mx, __shfl_xor(mx, o));
    if (lane == 0) red_s[wave] = mx;
    __syncthreads();
    mx = fmaxf(red_s[0], red_s[1]);
    float e = __expf(logit - mx);
    float sm = e;
    #pragma unroll
    for (int o = 1; o < 64; o <<= 1) sm += __shfl_xor(sm, o);
    if (lane == 0) red_s[2 + wave] = sm;
    __syncthreads();
    const float inv_denom = 1.0f / (red_s[2] + red_s[3]);
    sc_s[t] = e * inv_denom;
    __syncthreads();

    const float* vb = v + (size_t)b * M * D;
    float4 acc = {0.f, 0.f, 0.f, 0.f};
    #pragma unroll
    for (int j = 0; j < 16; ++j) {
        const int w = wbase + j * 4 + r;
        const float p = sc_s[w];
        const float4 vv = ((const float4*)(vb + (size_t)idx_s[w] * D))[ci];
        acc.x += p * vv.x; acc.y += p * vv.y;
        acc.z += p * vv.z; acc.w += p * vv.w;
    }
    acc.x += __shfl_xor(acc.x, 16); acc.y += __shfl_xor(acc.y, 16);
    acc.z += __shfl_xor(acc.z, 16); acc.w += __shfl_xor(acc.w, 16);
    acc.x += __shfl_xor(acc.x, 32); acc.y += __shfl_xor(acc.y, 32);
    acc.z += __shfl_xor(acc.z, 32); acc.w += __shfl_xor(acc.w, 32);

    if (wave == 0 && r == 0) opart_s[ci] = acc;
    __syncthreads();
    if (wave == 1 && r == 0) {
        const float4 o0 = opart_s[ci];
        float4 res;
        res.x = o0.x + acc.x; res.y = o0.y + acc.y;
        res.z = o0.z + acc.z; res.w = o0.w + acc.w;
        ((float4*)(out + ((size_t)b * M + m) * D))[ci] = res;
    }
}

extern "C" void kernel_launch(void* const* d_in, const int* in_sizes, int n_in,
                              void* d_out, int out_size, void* d_ws, size_t ws_size,
                              hipStream_t stream) {
    const float* q = (const float*)d_in[0];
    const float* k = (const float*)d_in[1];
    const float* v = (const float*)d_in[2];
    const int* idx = (const int*)d_in[3];
    float* out = (float*)d_out;

    const size_t need = (size_t)2 * NELEM * sizeof(__half);  // 4 MiB
    if (ws_size >= need) {
        __half* kh = (__half*)d_ws;
        __half* vh = kh + NELEM;
        const int n4 = NELEM / 4;
        const int cblk = (2 * n4 + 255) / 256;
        cvt_f32_f16_2<<<cblk, 256, 0, stream>>>((const float4*)k, (const float4*)v,
                                                (__half2*)kh, (__half2*)vh, n4);
        // 2 waves per block, wave-per-row; grid = B*M/2
        sparse_attn_f16<<<B * M / 2, 128, 0, stream>>>(q, kh, vh, idx, out);
    } else {
        sparse_attn_f32<<<B * M, 128, 0, stream>>>(q, k, v, idx, out);
    }
}